// Round 8
// baseline (528.234 us; speedup 1.0000x reference)
//
#include <hip/hip_runtime.h>

// h_t = alpha_t*h_{t-1} + x_t along S per (b,d). B=4, S=8192, D=1024, fp32.
// Round-8: REGISTER-RESIDENT single-read scan.
//   Model (r0-r7): per-CU vector READ path caps ~11-12 GB/s/CU regardless of
//   source (HBM or L3); writes ride a separate path. So the roofline currency
//   is logical READS. r5 read 539 MB (inputs + pass-B re-read); this kernel
//   reads 268 MB: each thread holds its 32-row chunk column in VGPRs
//   (64 float4 = 256 VGPR) across the sweep, then emits from registers.
//   1024 blocks x 256 thr; launch_bounds(256,4) -> VGPR<=512 (no spill) AND
//   guaranteed 4 blocks/CU co-residency for the grid barrier.
//   Barrier = padded 2-level tree (32 leaves x 32 arrivals) - avoids r6's
//   1024-deep single-cacheline atomic serialization.
constexpr int B    = 4;
constexpr int S    = 8192;
constexpr int D    = 1024;
constexpr int CB   = 256;        // chunks per batch
constexpr int L    = S / CB;     // 32 rows per chunk
constexpr int D4   = D / 4;      // 256 float4 per row = one 256-thread block
constexpr int NBLK = B * CB;     // 1024 blocks = 4 per CU (co-resident by launch_bounds)
constexpr int NLEAF   = 32;
constexpr int PERLEAF = NBLK / NLEAF;   // 32 arrivals per leaf line

typedef float nt_float4 __attribute__((ext_vector_type(4)));

struct Bar {                     // leaves padded to 64B each; root on its own line
    int leaf[NLEAF * 16];
    int root;
    int pad[15];
};

// Agent-scope (cross-XCD coherent) accessors.
__device__ __forceinline__ void ast(float* p, float v) {
    __hip_atomic_store(p, v, __ATOMIC_RELAXED, __HIP_MEMORY_SCOPE_AGENT);
}
__device__ __forceinline__ float ald(const float* p) {
    return __hip_atomic_load(p, __ATOMIC_RELAXED, __HIP_MEMORY_SCOPE_AGENT);
}

// Two-level grid barrier: 32 leaf counters (64B apart) -> root. Max serial
// atomic chain per cacheline = 32 (vs 1024 in r6's flat barrier).
__device__ __forceinline__ void gridbar(Bar* bar, int bid) {
    __syncthreads();                       // all waves' stores issued before arrival
    if (threadIdx.x == 0) {
        const int lf = (bid & (NLEAF - 1)) * 16;
        const int prev = __hip_atomic_fetch_add(&bar->leaf[lf], 1,
                                                __ATOMIC_ACQ_REL, __HIP_MEMORY_SCOPE_AGENT);
        if (prev == PERLEAF - 1)
            __hip_atomic_fetch_add(&bar->root, 1, __ATOMIC_ACQ_REL, __HIP_MEMORY_SCOPE_AGENT);
        while (__hip_atomic_load(&bar->root, __ATOMIC_RELAXED, __HIP_MEMORY_SCOPE_AGENT) < NLEAF)
            __builtin_amdgcn_s_sleep(2);
        __threadfence();                   // acquire side
    }
    __syncthreads();
}

__global__ __launch_bounds__(256, 4) void scan_reg(const float4* __restrict__ x,
                                                   const float4* __restrict__ a,
                                                   float4* __restrict__ out,
                                                   float* __restrict__ Xagg,
                                                   float* __restrict__ Aagg,
                                                   float* __restrict__ Pref,
                                                   Bar* __restrict__ bars) {
    const int t   = threadIdx.x;
    const int bid = blockIdx.x;
    const int b   = bid >> 8;              // batch (CB=256)
    const int c   = bid & (CB - 1);        // chunk
    const long base = ((long)(b * S + c * L)) * D4 + t;

    // ---- Load chunk ONCE into registers: 64 independent dwordx4. ----
    float4 Xs[L], Ps[L];
    #pragma unroll
    for (int s = 0; s < L; ++s) {
        Xs[s] = x[base + (long)s * D4];
        Ps[s] = a[base + (long)s * D4];
    }
    // ---- In-place zero-seed scan: Xs[s]=h_s(h_in=0), Ps[s]=prod(alpha_0..s).
    #pragma unroll
    for (int s = 1; s < L; ++s) {
        Xs[s].x = fmaf(Ps[s].x, Xs[s-1].x, Xs[s].x);
        Xs[s].y = fmaf(Ps[s].y, Xs[s-1].y, Xs[s].y);
        Xs[s].z = fmaf(Ps[s].z, Xs[s-1].z, Xs[s].z);
        Xs[s].w = fmaf(Ps[s].w, Xs[s-1].w, Xs[s].w);
        Ps[s].x *= Ps[s-1].x; Ps[s].y *= Ps[s-1].y;
        Ps[s].z *= Ps[s-1].z; Ps[s].w *= Ps[s-1].w;
    }
    // ---- Publish chunk aggregate (last row). Layout [record bid][D]. ----
    {
        float* Xp = Xagg + (long)bid * D + 4 * t;
        float* Ap = Aagg + (long)bid * D + 4 * t;
        ast(Xp + 0, Xs[L-1].x); ast(Xp + 1, Xs[L-1].y);
        ast(Xp + 2, Xs[L-1].z); ast(Xp + 3, Xs[L-1].w);
        ast(Ap + 0, Ps[L-1].x); ast(Ap + 1, Ps[L-1].y);
        ast(Ap + 2, Ps[L-1].z); ast(Ap + 3, Ps[L-1].w);
    }

    gridbar(bars + 0, bid);

    // ---- Sweep: 16 blocks, 1 thread per (batch, channel), 8-deep pipelined. ----
    if (bid < 16) {
        const int gg = bid * 256 + t;      // 0..4095
        const int sb = gg >> 10;           // batch
        const int d  = gg & (D - 1);       // channel
        const float* Xp = Xagg + (long)sb * CB * D + d;   // stride D along chunks
        const float* Ap = Aagg + (long)sb * CB * D + d;
        float*       Pp = Pref + (long)sb * CB * D + d;
        float carry = 0.f;
        for (int cc = 0; cc < CB; cc += 8) {
            float xv[8], av[8];
            #pragma unroll
            for (int j = 0; j < 8; ++j) {  // 16 independent loads in flight
                xv[j] = ald(Xp + (long)(cc + j) * D);
                av[j] = ald(Ap + (long)(cc + j) * D);
            }
            #pragma unroll
            for (int j = 0; j < 8; ++j) {  // serial part: 8 fmas
                ast(Pp + (long)(cc + j) * D, carry);      // exclusive prefix
                carry = fmaf(av[j], carry, xv[j]);
            }
        }
    }

    gridbar(bars + 1, bid);

    // ---- Emit from registers: out_s = Xs[s] + Ps[s]*carry. ZERO re-reads. ----
    float4 carry;
    {
        const float* Pp = Pref + (long)bid * D + 4 * t;
        carry.x = ald(Pp + 0); carry.y = ald(Pp + 1);
        carry.z = ald(Pp + 2); carry.w = ald(Pp + 3);
    }
    nt_float4* ntout = (nt_float4*)out;
    #pragma unroll
    for (int s = 0; s < L; ++s) {
        nt_float4 hv = { fmaf(Ps[s].x, carry.x, Xs[s].x),
                         fmaf(Ps[s].y, carry.y, Xs[s].y),
                         fmaf(Ps[s].z, carry.z, Xs[s].z),
                         fmaf(Ps[s].w, carry.w, Xs[s].w) };
        __builtin_nontemporal_store(hv, &ntout[base + (long)s * D4]);
    }
}

extern "C" void kernel_launch(void* const* d_in, const int* in_sizes, int n_in,
                              void* d_out, int out_size, void* d_ws, size_t ws_size,
                              hipStream_t stream) {
    const float4* x = (const float4*)d_in[0];
    const float4* a = (const float4*)d_in[1];
    float4* out = (float4*)d_out;

    // Workspace: [2 x Bar, 8KB region] | Xagg 4MB | Aagg 4MB | Pref 4MB (~12 MiB).
    char* ws = (char*)d_ws;
    Bar*   bars = (Bar*)ws;
    float* Xagg = (float*)(ws + 8192);
    float* Aagg = Xagg + (size_t)NBLK * D;
    float* Pref = Aagg + (size_t)NBLK * D;

    hipMemsetAsync(ws, 0, 8192, stream);   // reset barrier counters (graph-capturable)
    scan_reg<<<dim3(NBLK), 256, 0, stream>>>(x, a, out, Xagg, Aagg, Pref, bars);
}